// Round 4
// baseline (216.730 us; speedup 1.0000x reference)
//
#include <hip/hip_runtime.h>
#include <hip/hip_fp16.h>

#define N_TOT 65536
#define D_DIM 512
#define K_DIM 64
#define NC    32                // n-rows per MFMA K-step
#define GSZ   (K_DIM * D_DIM)   // 32768 elements of partial G

typedef __bf16   bf16x8 __attribute__((ext_vector_type(8)));
typedef float    f32x4  __attribute__((ext_vector_type(4)));
typedef _Float16 half8  __attribute__((ext_vector_type(8)));

__device__ __forceinline__ unsigned int pack_bf16(float a, float b) {
    union { float f; unsigned int u; } x, y;
    x.f = a; y.f = b;
    unsigned int lo = (x.u + 0x7fffu + ((x.u >> 16) & 1u)) >> 16;   // RNE
    unsigned int hi = (y.u + 0x7fffu + ((y.u >> 16) & 1u)) >> 16;
    return lo | (hi << 16);
}

union pk4 { unsigned int u[4]; bf16x8 v; };

// K1: direct global->register->MFMA. No LDS staging, no __syncthreads in the
// K-loop (R3's 1-block/CU + block-wide barrier serialized every HBM latency).
// Fragment layouts (validated by R1-R3 passing kernels):
//   A[m=lane&15][n=q*8+j] = F[n0+q*8+j][kt*16+m]
//   B[d=lane&15][n=q*8+j] = h[n0+q*8+j][d0+m]
// Per-instruction addresses: 4 x 64B segments, every byte consumed once.
// All 16 waves issue identical F addresses -> L1 broadcast.
extern "C" __global__ void __launch_bounds__(1024)
k1_partial(const float* __restrict__ h, const float* __restrict__ F,
           float* __restrict__ trw_out, unsigned short* __restrict__ gpart,
           float* __restrict__ out, int rowsPerBlock) {
    __shared__ float red[16];

    const int tid = threadIdx.x;
    const int b   = blockIdx.x;
    if (b == 0 && tid == 0) out[0] = 0.0f;        // d_out poisoned; zero before K2

    const int wave = tid >> 6;    // 0..15 ; wave owns d in [32w, 32w+32)
    const int lane = tid & 63;
    const int m    = lane & 15;
    const int q    = lane >> 4;

    const int row0    = b * rowsPerBlock;
    const int nChunks = rowsPerBlock / NC;

    f32x4 acc[4][2];
    #pragma unroll
    for (int kt = 0; kt < 4; ++kt)
        #pragma unroll
        for (int dt = 0; dt < 2; ++dt)
            acc[kt][dt] = (f32x4){0.f, 0.f, 0.f, 0.f};

    float trw = 0.f;

    // lane-fixed base pointers (advance by NC rows per chunk)
    const float* hb = h + (size_t)(row0 + q * 8) * D_DIM + wave * 32 + m;
    const float* fb = F + (size_t)(row0 + q * 8) * K_DIM + m;

    for (int c = 0; c < nChunks; ++c) {
        // ---- B (h) : 16 batched loads, then pack + trw ----
        float vb[16];
        #pragma unroll
        for (int dt = 0; dt < 2; ++dt)
            #pragma unroll
            for (int j = 0; j < 8; ++j)
                vb[dt * 8 + j] = hb[(size_t)j * D_DIM + dt * 16];

        bf16x8 bfrag[2];
        #pragma unroll
        for (int dt = 0; dt < 2; ++dt) {
            pk4 p;
            #pragma unroll
            for (int jj = 0; jj < 4; ++jj) {
                float a0 = vb[dt * 8 + 2 * jj], a1 = vb[dt * 8 + 2 * jj + 1];
                trw += a0 * a0 + a1 * a1;
                p.u[jj] = pack_bf16(a0, a1);
            }
            bfrag[dt] = p.v;
        }

        // ---- A (F) : 2 rounds of 16 batched loads ----
        bf16x8 afrag[4];
        #pragma unroll
        for (int r = 0; r < 2; ++r) {
            float va[16];
            #pragma unroll
            for (int kk = 0; kk < 2; ++kk)
                #pragma unroll
                for (int j = 0; j < 8; ++j)
                    va[kk * 8 + j] = fb[(size_t)j * K_DIM + (r * 2 + kk) * 16];
            #pragma unroll
            for (int kk = 0; kk < 2; ++kk) {
                pk4 p;
                #pragma unroll
                for (int jj = 0; jj < 4; ++jj)
                    p.u[jj] = pack_bf16(va[kk * 8 + 2 * jj], va[kk * 8 + 2 * jj + 1]);
                afrag[r * 2 + kk] = p.v;
            }
        }

        // ---- 8 MFMAs ----
        #pragma unroll
        for (int kt = 0; kt < 4; ++kt)
            #pragma unroll
            for (int dt = 0; dt < 2; ++dt)
                acc[kt][dt] = __builtin_amdgcn_mfma_f32_16x16x32_bf16(
                    afrag[kt], bfrag[dt], acc[kt][dt], 0, 0, 0);

        hb += (size_t)NC * D_DIM;
        fb += (size_t)NC * K_DIM;
    }

    // ---- epilogue: partial G -> fp16 in workspace ----
    unsigned short* gp = gpart + (size_t)b * GSZ;
    #pragma unroll
    for (int kt = 0; kt < 4; ++kt)
        #pragma unroll
        for (int dt = 0; dt < 2; ++dt)
            #pragma unroll
            for (int r = 0; r < 4; ++r) {
                const int k = kt * 16 + q * 4 + r;      // C/D row = (lane>>4)*4 + reg
                const int d = wave * 32 + dt * 16 + m;  // C/D col = lane&15
                __half hv = __float2half(acc[kt][dt][r]);
                gp[k * D_DIM + d] = *(unsigned short*)&hv;
            }

    // ---- tr_wtw partial: wave shuffle reduce -> LDS -> one store ----
    #pragma unroll
    for (int off = 32; off > 0; off >>= 1) trw += __shfl_down(trw, off, 64);
    if (lane == 0) red[wave] = trw;
    __syncthreads();
    if (tid == 0) {
        float s = 0.f;
        #pragma unroll
        for (int w = 0; w < 16; ++w) s += red[w];
        trw_out[b] = s;
    }
}

// K2: out = sum_b trw[b] - sum_{k,d} (sum_b Gpart[b][k,d])^2   (256 blocks)
extern "C" __global__ void __launch_bounds__(512)
k2_reduce(const float* __restrict__ trw, const unsigned short* __restrict__ gpart,
          float* __restrict__ out, int P) {
    __shared__ float sh[32 * 16 * 8];   // 16 KB: [sub][oct][j]
    __shared__ float red2[8];

    const int tid = threadIdx.x;
    const int sub = tid >> 4;                  // 0..31 : b-split
    const int oct = tid & 15;
    const int tt  = blockIdx.x * 16 + oct;     // 0..4095 ; elements 8tt..8tt+7

    float g[8];
    #pragma unroll
    for (int j = 0; j < 8; ++j) g[j] = 0.f;

    const unsigned short* base = gpart + (size_t)tt * 8;
    for (int b = sub; b < P; b += 32) {
        half8 v = *(const half8*)(base + (size_t)b * GSZ);
        #pragma unroll
        for (int j = 0; j < 8; ++j) g[j] += (float)v[j];
    }
    #pragma unroll
    for (int j = 0; j < 8; ++j) sh[(sub * 16 + oct) * 8 + j] = g[j];
    __syncthreads();

    float val = 0.f;
    if (tid < 128) {
        const int o2 = tid >> 3, j = tid & 7;
        float s = 0.f;
        #pragma unroll
        for (int sb = 0; sb < 32; ++sb) s += sh[(sb * 16 + o2) * 8 + j];
        val = -s * s;
    } else if (blockIdx.x == 0 && tid - 128 < P) {
        val = trw[tid - 128];                  // fold tr_wtw partials in block 0
    }

    #pragma unroll
    for (int off = 32; off > 0; off >>= 1) val += __shfl_down(val, off, 64);
    if ((tid & 63) == 0) red2[tid >> 6] = val;
    __syncthreads();
    if (tid == 0) {
        float s = 0.f;
        #pragma unroll
        for (int w = 0; w < 8; ++w) s += red2[w];
        atomicAdd(out, s);
    }
}

extern "C" void kernel_launch(void* const* d_in, const int* in_sizes, int n_in,
                              void* d_out, int out_size, void* d_ws, size_t ws_size,
                              hipStream_t stream) {
    const float* h = (const float*)d_in[0];   // [65536, 512]
    const float* F = (const float*)d_in[1];   // [65536, 64]
    float* out = (float*)d_out;

    // ws layout: [0,4096): trw fp32 (P<=256) ; [4096, 4096+P*64KiB): fp16 partial G
    int P = 256;
    while (P > 1 && (size_t)4096 + (size_t)P * (GSZ * 2) > ws_size) P >>= 1;
    const int rowsPerBlock = N_TOT / P;

    float* trw = (float*)d_ws;
    unsigned short* gpart = (unsigned short*)((char*)d_ws + 4096);

    hipLaunchKernelGGL(k1_partial, dim3(P), dim3(1024), 0, stream,
                       h, F, trw, gpart, out, rowsPerBlock);
    hipLaunchKernelGGL(k2_reduce, dim3(256), dim3(512), 0, stream,
                       trw, gpart, out, P);
}